// Round 5
// baseline (37.612 us; speedup 1.0000x reference)
//
#include <hip/hip_runtime.h>
#include <hip/hip_bf16.h>

#define D_MODEL 4096
#define NN      4403      // selected neurons
#define NB      64        // batch
#define BN      64        // neurons per block (4 waves x 16)
#define KCH     512       // K per block in GEMM stage
#define KSPLIT  (D_MODEL / KCH)   // 8
#define LDX     520       // shorts per X row in LDS (pad -> conflict-free frag reads)
#define OUT_ELEMS (NB * NN)       // 281792
#define PART_FLOATS ((size_t)KSPLIT * OUT_ELEMS)          // 2,254,336
#define PART_BYTES  (PART_FLOATS * 4)                     // 9,017,344
#define G_BYTES     ((size_t)NN * D_MODEL * 2)            // 36,069,376
#define XBF_BYTES   ((size_t)NB * D_MODEL * 2)            // 524,288
#define WS_NEEDED   (PART_BYTES + G_BYTES + XBF_BYTES)    // ~45.6 MB

using f32x4  = __attribute__((ext_vector_type(4))) float;
using bf16x8 = __attribute__((ext_vector_type(8))) short;
using u16x8  = __attribute__((ext_vector_type(8))) unsigned short;

__device__ __forceinline__ unsigned short f2bf(float f) {
    __hip_bfloat16 h = __float2bfloat16(f);     // RNE
    return __builtin_bit_cast(unsigned short, h);
}

__device__ __forceinline__ u16x8 pack8(f32x4 a, f32x4 b) {
    u16x8 v;
    v[0] = f2bf(a[0]); v[1] = f2bf(a[1]); v[2] = f2bf(a[2]); v[3] = f2bf(a[3]);
    v[4] = f2bf(b[0]); v[5] = f2bf(b[1]); v[6] = f2bf(b[2]); v[7] = f2bf(b[3]);
    return v;
}

// ---------------- Stage A: full-row gather + fp32->bf16 compact ----------------
// One wave per row. Each W row is read as ONE contiguous 16 KB stream
// (DRAM page-friendly), written as 8 KB bf16 to compact G in ws (L3-resident).
// Rows [NN, NN+64) convert X instead.
__global__ __launch_bounds__(256)
void gather_compact(const float* __restrict__ W,
                    const float* __restrict__ X,
                    const int*   __restrict__ idx,
                    unsigned short* __restrict__ G,
                    unsigned short* __restrict__ Xbf)
{
    const int r    = blockIdx.x * 4 + (threadIdx.x >> 6);
    const int lane = threadIdx.x & 63;

    const float* src;
    unsigned short* dst;
    if (r < NN) {
        src = W + (size_t)idx[r] * D_MODEL;
        dst = G + (size_t)r * D_MODEL;
    } else if (r < NN + NB) {
        src = X + (size_t)(r - NN) * D_MODEL;
        dst = Xbf + (size_t)(r - NN) * D_MODEL;
    } else {
        return;
    }

#pragma unroll
    for (int it = 0; it < 8; ++it) {
        const float* s = src + it * 512 + lane * 8;
        f32x4 a = *(const f32x4*)(s + 0);
        f32x4 b = *(const f32x4*)(s + 4);
        *(u16x8*)(dst + it * 512 + lane * 8) = pack8(a, b);
    }
}

// ---------------- Stage B: bf16 GEMM on compact G (L3-hot) ----------------
__global__ __launch_bounds__(256, 2)
void gemm_compact(const unsigned short* __restrict__ G,
                  const unsigned short* __restrict__ Xbf,
                  float* __restrict__ partial)
{
    __shared__ __align__(16) unsigned short Xs[64 * LDX];   // 66.5 KB

    const int tid   = threadIdx.x;
    const int wave  = tid >> 6;
    const int lane  = tid & 63;
    const int n0    = blockIdx.x * BN;
    const int kbase = blockIdx.y * KCH;

    const int fr = lane & 15;
    const int g  = lane >> 4;
    const int fk = g * 8;

    // per-lane B-operand prefetch from compact G (bf16, no cvt, no idx chase)
    const int n  = n0 + wave * 16 + fr;
    const int nc = (n < NN) ? n : (NN - 1);
    const unsigned short* gp = G + (size_t)nc * D_MODEL + kbase + fk;

    bf16x8 wfrag[16];
#pragma unroll
    for (int s = 0; s < 16; ++s) wfrag[s] = *(const bf16x8*)(gp + s * 32);

    // X panel staging: 64 rows x 512 bf16 from Xbf (L2-hot), no conversion
    {
        const int row = tid >> 2;      // 0..63
        const int q   = tid & 3;
#pragma unroll
        for (int c = 0; c < 16; ++c) {
            const int slot = c * 4 + q;                    // 0..63 16B-slots per row
            u16x8 v = *(const u16x8*)(Xbf + (size_t)row * D_MODEL + kbase + slot * 8);
            *(u16x8*)&Xs[row * LDX + slot * 8] = v;
        }
    }
    __syncthreads();

    f32x4 acc[4];
#pragma unroll
    for (int m = 0; m < 4; ++m) acc[m] = (f32x4){0.f, 0.f, 0.f, 0.f};

#pragma unroll
    for (int s = 0; s < 16; ++s) {
#pragma unroll
        for (int m = 0; m < 4; ++m) {
            bf16x8 afrag = *(const bf16x8*)&Xs[(m * 16 + fr) * LDX + s * 32 + fk];
            acc[m] = __builtin_amdgcn_mfma_f32_16x16x32_bf16(afrag, wfrag[s], acc[m], 0, 0, 0);
        }
    }

    // C/D layout: col = lane&15 (neuron), row = (lane>>4)*4 + reg (batch)
    const int ncol = n0 + wave * 16 + fr;
    if (ncol < NN) {
        float* base = partial + (size_t)blockIdx.y * OUT_ELEMS;
#pragma unroll
        for (int m = 0; m < 4; ++m) {
            int brow = m * 16 + g * 4;
#pragma unroll
            for (int r = 0; r < 4; ++r)
                base[(size_t)(brow + r) * NN + ncol] = acc[m][r];
        }
    }
}

// ---------------- Stage C: split-K reduce ----------------
__global__ __launch_bounds__(256)
void reduce_splitk(const float* __restrict__ p, float* __restrict__ out) {
    const int i = blockIdx.x * 256 + threadIdx.x;        // float4 index
    const int n4 = OUT_ELEMS / 4;                        // 70448
    if (i >= n4) return;
    const f32x4* p4 = (const f32x4*)p;
    f32x4 a = p4[i];
#pragma unroll
    for (int s = 1; s < KSPLIT; ++s) a += p4[(size_t)s * n4 + i];
    ((f32x4*)out)[i] = a;
}

// ---------------- Fallback (ws too small): one-pass atomic version ----------------
__global__ __launch_bounds__(256, 2)
void gather_gemm_atomic(const float* __restrict__ X,
                        const float* __restrict__ W,
                        const int*   __restrict__ idx,
                        float* __restrict__ out)
{
    __shared__ __align__(16) unsigned short Xs[64 * LDX];

    const int tid   = threadIdx.x;
    const int wave  = tid >> 6;
    const int lane  = tid & 63;
    const int n0    = blockIdx.x * BN;
    const int kbase = blockIdx.y * KCH;
    const int fr = lane & 15;
    const int g  = lane >> 4;
    const int fk = g * 8;

    const int n    = n0 + wave * 16 + fr;
    const int wrow = (n < NN) ? idx[n] : 0;
    const float* wp = W + (size_t)wrow * D_MODEL + kbase + fk;

    f32x4 wraw[16][2];
#pragma unroll
    for (int s = 0; s < 16; ++s) {
        wraw[s][0] = *(const f32x4*)(wp + s * 32);
        wraw[s][1] = *(const f32x4*)(wp + s * 32 + 4);
    }
    {
        const int row8 = tid >> 5;
        const int colf = tid & 31;
#pragma unroll
        for (int c = 0; c < 8; ++c) {
            const int row = c * 8 + row8;
            const float* xp = X + (size_t)row * D_MODEL + kbase + colf * 16;
            f32x4 a0 = *(const f32x4*)(xp + 0);
            f32x4 a1 = *(const f32x4*)(xp + 4);
            f32x4 a2 = *(const f32x4*)(xp + 8);
            f32x4 a3 = *(const f32x4*)(xp + 12);
            *(u16x8*)&Xs[row * LDX + colf * 16 + 0] = pack8(a0, a1);
            *(u16x8*)&Xs[row * LDX + colf * 16 + 8] = pack8(a2, a3);
        }
    }
    __syncthreads();

    f32x4 acc[4];
#pragma unroll
    for (int m = 0; m < 4; ++m) acc[m] = (f32x4){0.f, 0.f, 0.f, 0.f};
#pragma unroll
    for (int s = 0; s < 16; ++s) {
        bf16x8 bfrag = __builtin_bit_cast(bf16x8, pack8(wraw[s][0], wraw[s][1]));
#pragma unroll
        for (int m = 0; m < 4; ++m) {
            bf16x8 afrag = *(const bf16x8*)&Xs[(m * 16 + fr) * LDX + s * 32 + fk];
            acc[m] = __builtin_amdgcn_mfma_f32_16x16x32_bf16(afrag, bfrag, acc[m], 0, 0, 0);
        }
    }
    const int ncol = n0 + wave * 16 + fr;
    if (ncol < NN) {
#pragma unroll
        for (int m = 0; m < 4; ++m) {
            int brow = m * 16 + g * 4;
#pragma unroll
            for (int r = 0; r < 4; ++r)
                atomicAdd(&out[(size_t)(brow + r) * NN + ncol], acc[m][r]);
        }
    }
}

extern "C" void kernel_launch(void* const* d_in, const int* in_sizes, int n_in,
                              void* d_out, int out_size, void* d_ws, size_t ws_size,
                              hipStream_t stream) {
    const float* X   = (const float*)d_in[0];   // [64,1,4096] f32
    const float* W   = (const float*)d_in[1];   // [11008,4096] f32
    const int*   idx = (const int*)d_in[2];     // [4403] i32
    float* out = (float*)d_out;                 // [64,1,4403] f32

    if (ws_size >= WS_NEEDED) {
        float*          partial = (float*)d_ws;
        unsigned short* G   = (unsigned short*)((char*)d_ws + PART_BYTES);
        unsigned short* Xbf = (unsigned short*)((char*)d_ws + PART_BYTES + G_BYTES);

        // Stage A: 4467 rows (4403 gathered W rows + 64 X rows), 1 wave each
        int rows = NN + NB;
        gather_compact<<<(rows + 3) / 4, 256, 0, stream>>>(W, X, idx, G, Xbf);

        // Stage B: bf16 GEMM on compact G
        dim3 grid((NN + BN - 1) / BN, KSPLIT, 1);   // 69 x 8
        gemm_compact<<<grid, 256, 0, stream>>>(G, Xbf, partial);

        // Stage C: reduce split-K partials
        int n4 = OUT_ELEMS / 4;
        reduce_splitk<<<(n4 + 255) / 256, 256, 0, stream>>>(partial, out);
    } else {
        hipMemsetAsync(d_out, 0, (size_t)out_size * sizeof(float), stream);
        dim3 grid((NN + BN - 1) / BN, KSPLIT, 1);
        gather_gemm_atomic<<<grid, 256, 0, stream>>>(X, W, idx, out);
    }
}